// Round 6
// baseline (5272.148 us; speedup 1.0000x reference)
//
#include <hip/hip_runtime.h>

#define NN 100000
#define NE 1600000
#define FIN 128
#define HID 64
#define HEADS 8
#define KORD 14
#define NGRAPHS 128
#define NCLASSES 10

static inline size_t align256(size_t x) { return (x + 255) & ~(size_t)255; }

// round-to-nearest-even f32 -> bf16 (as uint16 in low bits)
__device__ __forceinline__ unsigned bfr(float x) {
    unsigned u = __float_as_uint(x);
    return (u + 0x7fffu + ((u >> 16) & 1u)) >> 16;
}
__device__ __forceinline__ unsigned bfpack(float lo, float hi) {
    return bfr(lo) | (bfr(hi) << 16);
}
__device__ __forceinline__ float bflo(unsigned u) { return __uint_as_float(u << 16); }
__device__ __forceinline__ float bfhi(unsigned u) { return __uint_as_float(u & 0xffff0000u); }

// ---------------- setup kernels ----------------

__global__ void k_deg(const int* __restrict__ row, int* __restrict__ deg, int ne) {
    int e = blockIdx.x * 256 + threadIdx.x;
    if (e < ne) atomicAdd(&deg[row[e]], 1);
}

// dinv = rsqrt(max(deg,1)); d2 = 1/max(deg,1); rdinv = sqrt(max(deg,1))
__global__ void k_dinv(const int* __restrict__ deg, float* __restrict__ dinv,
                       float* __restrict__ d2, float* __restrict__ rdinv, int n) {
    int i = blockIdx.x * 256 + threadIdx.x;
    if (i < n) {
        float d = (float)deg[i];
        if (d < 1.f) d = 1.f;
        dinv[i] = rsqrtf(d);
        d2[i] = 1.f / d;
        rdinv[i] = sqrtf(d);
    }
}

// exclusive scan phase 1: per-block scan of PADDED degrees ((deg+7)&~7)
__global__ void k_scan1(const int* __restrict__ deg, int* __restrict__ rowptr,
                        int* __restrict__ bsum, int n) {
    __shared__ int s[256];
    int t = threadIdx.x;
    int i = blockIdx.x * 256 + t;
    int v = (i < n) ? ((deg[i] + 7) & ~7) : 0;
    s[t] = v;
    __syncthreads();
    for (int off = 1; off < 256; off <<= 1) {
        int add = (t >= off) ? s[t - off] : 0;
        __syncthreads();
        s[t] += add;
        __syncthreads();
    }
    if (i < n) rowptr[i] = s[t] - v;  // exclusive within block
    if (t == 255) bsum[blockIdx.x] = s[255];
}

// phase 2: single-block exclusive scan of block sums (nb <= 1024)
__global__ void k_scan2(int* __restrict__ bsum, int nb) {
    __shared__ int s[1024];
    int t = threadIdx.x;
    int v = (t < nb) ? bsum[t] : 0;
    s[t] = v;
    __syncthreads();
    for (int off = 1; off < 1024; off <<= 1) {
        int add = (t >= off) ? s[t - off] : 0;
        __syncthreads();
        s[t] += add;
        __syncthreads();
    }
    if (t < nb) bsum[t] = s[t] - v;  // exclusive
}

// phase 3: add block offsets; init cursor; write rowptr[n] (total padded edges)
__global__ void k_scan3(int* __restrict__ rowptr, int* __restrict__ cursor,
                        const int* __restrict__ bsum, const int* __restrict__ deg, int n) {
    int i = blockIdx.x * 256 + threadIdx.x;
    if (i < n) {
        int v = rowptr[i] + bsum[i >> 8];
        rowptr[i] = v;
        cursor[i] = v;
        if (i == n - 1) rowptr[n] = v + ((deg[i] + 7) & ~7);
    }
}

// pre-fill ccol with the zero-row index n (pad slots read row n == 0)
__global__ void k_filln(int* __restrict__ ccol, int npad, int n) {
    int i = blockIdx.x * 256 + threadIdx.x;
    if (i < npad) ccol[i] = n;
}

// fill CSR cols (weights are implicit in S-space)
__global__ void k_fill(const int* __restrict__ row, const int* __restrict__ col,
                       int* __restrict__ cursor, int* __restrict__ ccol, int ne) {
    int e = blockIdx.x * 256 + threadIdx.x;
    if (e >= ne) return;
    int pos = atomicAdd(&cursor[row[e]], 1);
    ccol[pos] = col[e];
}

// zero the pad row (row n) of all 7 slabs x 4 planes
__global__ void k_zrow(unsigned* __restrict__ slabs, int PSd, int n) {
    int t = threadIdx.x;
    if (t >= 7 * 4 * 8) return;
    int sp = t >> 3;  // slab*4+plane, 0..27
    int q = t & 7;
    slabs[(size_t)sp * PSd + (size_t)n * 8 + q] = 0;
}

// coeff[l][k] = mean over heads of theta[l][h][k]
__global__ void k_coeff(const float* __restrict__ th1, const float* __restrict__ ths,
                        float* __restrict__ coeff) {
    int i = threadIdx.x;
    if (i >= 3 * KORD) return;
    int l = i / KORD, k = i % KORD;
    const float* t = (l == 0) ? th1 : ths + (l - 1) * HEADS * KORD;
    float s = 0.f;
    for (int h = 0; h < HEADS; ++h) s += t[h * KORD + k];
    coeff[i] = s * (1.f / HEADS);
}

// ---------------- main compute kernels ----------------

// S0 = dinv * (h @ W), written as bf16 into 4 feature planes of slab0.
// block = 256 threads, tile = 64 rows x 64 cols, thread computes 4 rows x 4 cols.
template <int F>
__global__ __launch_bounds__(256) void k_gemm(const float* __restrict__ h,
                                              const float* __restrict__ W,
                                              unsigned* __restrict__ slab0,
                                              const float* __restrict__ dinv,
                                              int n, int PSd) {
    __shared__ __align__(16) float Wl[F * 64];
    __shared__ float hl[64][F + 1];
    int tid = threadIdx.x;
    int row0 = blockIdx.x * 64;
    int nrows = n - row0;
    if (nrows > 64) nrows = 64;

    for (int i = tid; i < F * 64; i += 256) Wl[i] = W[i];
    for (int i = tid; i < nrows * F; i += 256) hl[i / F][i % F] = h[(size_t)row0 * F + i];
    __syncthreads();

    int rq = tid >> 4;        // 0..15 -> rows rq*4 .. rq*4+3
    int c0 = (tid & 15) * 4;  // col group
    float4 acc0 = {0, 0, 0, 0}, acc1 = {0, 0, 0, 0}, acc2 = {0, 0, 0, 0}, acc3 = {0, 0, 0, 0};
#pragma unroll 4
    for (int f = 0; f < F; ++f) {
        const float4 wv = *(const float4*)&Wl[f * 64 + c0];
        float h0 = hl[rq * 4 + 0][f];
        float h1 = hl[rq * 4 + 1][f];
        float h2 = hl[rq * 4 + 2][f];
        float h3 = hl[rq * 4 + 3][f];
        acc0.x = fmaf(h0, wv.x, acc0.x); acc0.y = fmaf(h0, wv.y, acc0.y);
        acc0.z = fmaf(h0, wv.z, acc0.z); acc0.w = fmaf(h0, wv.w, acc0.w);
        acc1.x = fmaf(h1, wv.x, acc1.x); acc1.y = fmaf(h1, wv.y, acc1.y);
        acc1.z = fmaf(h1, wv.z, acc1.z); acc1.w = fmaf(h1, wv.w, acc1.w);
        acc2.x = fmaf(h2, wv.x, acc2.x); acc2.y = fmaf(h2, wv.y, acc2.y);
        acc2.z = fmaf(h2, wv.z, acc2.z); acc2.w = fmaf(h2, wv.w, acc2.w);
        acc3.x = fmaf(h3, wv.x, acc3.x); acc3.y = fmaf(h3, wv.y, acc3.y);
        acc3.z = fmaf(h3, wv.z, acc3.z); acc3.w = fmaf(h3, wv.w, acc3.w);
    }
    int rem = nrows - rq * 4;
    float4 accs[4] = {acc0, acc1, acc2, acc3};
    int pl = c0 >> 4;
    int qd = (c0 & 15) >> 1;  // even dword offset within plane row
#pragma unroll
    for (int r = 0; r < 4; ++r) {
        if (r < rem) {
            int row = row0 + rq * 4 + r;
            float dv = dinv[row];
            size_t dw = (size_t)pl * PSd + (size_t)row * 8 + qd;
            uint2 p;
            p.x = bfpack(accs[r].x * dv, accs[r].y * dv);
            p.y = bfpack(accs[r].z * dv, accs[r].w * dv);
            *(uint2*)(slab0 + dw) = p;
        }
    }
}

// S-space Chebyshev prop, one feature plane (16 feats) per block, 4 rows/block (1/wave).
// lane: g = lane>>3 (edge slot), fl = lane&7 (feature dword = 2 bf16).
// sum_r = sum over row's edges of S_src[col]; rows padded to x8 with col=n (zero row).
// FIRST: S1 = -d2 * sum ; else: S_k = -2*d2*sum - S_{k-2}
// blockIdx&7 -> XCD slot: plane = slot>>1 (pins each plane to one XCD pair for L2 residency).
template <bool FIRST>
__global__ __launch_bounds__(256) void k_prop(const int* __restrict__ rowptr,
                                              const int* __restrict__ ccol,
                                              const unsigned* __restrict__ src,
                                              const unsigned* __restrict__ prev,
                                              unsigned* __restrict__ dst,
                                              const float* __restrict__ d2arr,
                                              int n, int PSd, int RB) {
    int blk = blockIdx.x;
    int slot = blk & 7;
    int pl = slot >> 1;
    int rb = (blk >> 3) * 2 + (slot & 1);
    if (rb >= RB) return;
    int wave = threadIdx.x >> 6;
    int lane = threadIdx.x & 63;
    int r = rb * 4 + wave;
    if (r >= n) return;
    const unsigned* sp = src + (size_t)pl * PSd;
    const int e0 = rowptr[r];
    const int e1 = rowptr[r + 1];
    const int g = lane >> 3;
    const int fl = lane & 7;
    float a0 = 0.f, a1 = 0.f;
    int e = e0;
    int c = (e < e1) ? ccol[e + g] : 0;
    while (e < e1) {
        int en = e + 8;
        int cn = (en < e1) ? ccol[en + g] : 0;
        unsigned u = sp[(size_t)c * 8 + fl];
        a0 += bflo(u);
        a1 += bfhi(u);
        c = cn;
        e = en;
    }
    a0 += __shfl_xor(a0, 8, 64);
    a1 += __shfl_xor(a1, 8, 64);
    a0 += __shfl_xor(a0, 16, 64);
    a1 += __shfl_xor(a1, 16, 64);
    a0 += __shfl_xor(a0, 32, 64);
    a1 += __shfl_xor(a1, 32, 64);
    if (lane >= 8) return;
    float d2 = d2arr[r];
    size_t di = (size_t)pl * PSd + (size_t)r * 8 + fl;
    float sx, sy;
    if (FIRST) {
        sx = -d2 * a0;
        sy = -d2 * a1;
    } else {
        unsigned pu = prev[di];
        sx = fmaf(-2.f * d2, a0, -bflo(pu));
        sy = fmaf(-2.f * d2, a1, -bfhi(pu));
    }
    dst[di] = bfpack(sx, sy);
}

// accumulate 7 Chebyshev terms: out(+)= rdinv[r] * sum_j cf[j]*S_j ; FINAL adds bias+relu.
template <bool FINAL>
__global__ __launch_bounds__(256) void k_acc(const unsigned* __restrict__ s0,
                                             const unsigned* __restrict__ s1,
                                             const unsigned* __restrict__ s2,
                                             const unsigned* __restrict__ s3,
                                             const unsigned* __restrict__ s4,
                                             const unsigned* __restrict__ s5,
                                             const unsigned* __restrict__ s6,
                                             const float* __restrict__ cf,
                                             const float* __restrict__ bias,
                                             const float* __restrict__ rdinv,
                                             float* __restrict__ outacc, int n, int PSd) {
    int i = blockIdx.x * 256 + threadIdx.x;
    if (i >= n * 32) return;
    int r = i >> 5;
    int f0 = (i & 31) * 2;
    size_t dw = (size_t)(f0 >> 4) * PSd + (size_t)r * 8 + ((f0 & 15) >> 1);
    float c0 = cf[0], c1 = cf[1], c2 = cf[2], c3 = cf[3], c4 = cf[4], c5 = cf[5], c6 = cf[6];
    unsigned u;
    float ax, ay;
    u = s0[dw]; ax = c0 * bflo(u); ay = c0 * bfhi(u);
    u = s1[dw]; ax = fmaf(c1, bflo(u), ax); ay = fmaf(c1, bfhi(u), ay);
    u = s2[dw]; ax = fmaf(c2, bflo(u), ax); ay = fmaf(c2, bfhi(u), ay);
    u = s3[dw]; ax = fmaf(c3, bflo(u), ax); ay = fmaf(c3, bfhi(u), ay);
    u = s4[dw]; ax = fmaf(c4, bflo(u), ax); ay = fmaf(c4, bfhi(u), ay);
    u = s5[dw]; ax = fmaf(c5, bflo(u), ax); ay = fmaf(c5, bfhi(u), ay);
    u = s6[dw]; ax = fmaf(c6, bflo(u), ax); ay = fmaf(c6, bfhi(u), ay);
    float rd = rdinv[r];
    ax *= rd;
    ay *= rd;
    float2* op = (float2*)outacc + i;
    if (FINAL) {
        float2 pv = *op;
        float vx = pv.x + ax + bias[f0];
        float vy = pv.y + ay + bias[f0 + 1];
        *op = make_float2(vx > 0.f ? vx : 0.f, vy > 0.f ? vy : 0.f);
    } else {
        *op = make_float2(ax, ay);
    }
}

// run-length compressed segment sum over sorted batch; wave = 32 nodes, lane = feature
__global__ void k_pool(const float* __restrict__ h, const int* __restrict__ batch,
                       float* __restrict__ sums, float* __restrict__ cntf, int n) {
    int wid = (blockIdx.x * blockDim.x + threadIdx.x) >> 6;
    int lane = threadIdx.x & 63;
    int start = wid * 32;
    if (start >= n) return;
    int end = start + 32;
    if (end > n) end = n;
    float acc = 0.f;
    int run = 0;
    int g = batch[start];
    for (int i = start; i < end; ++i) {
        int gi = batch[i];
        if (gi != g) {
            atomicAdd(&sums[g * 64 + lane], acc);
            if (lane == 0) atomicAdd(&cntf[g], (float)run);
            acc = 0.f;
            run = 0;
            g = gi;
        }
        acc += h[(size_t)i * 64 + lane];
        run++;
    }
    atomicAdd(&sums[g * 64 + lane], acc);
    if (lane == 0) atomicAdd(&cntf[g], (float)run);
}

// per-graph head: pooled = sums/cnt ; g = relu(pooled@w1+b1) ; logits = g@w2+b2 ; log_softmax
__global__ void k_head(const float* __restrict__ sums, const float* __restrict__ cntf,
                       const float* __restrict__ w1, const float* __restrict__ b1,
                       const float* __restrict__ w2, const float* __restrict__ b2,
                       float* __restrict__ out) {
    __shared__ float pl[64], gl[64], lg[NCLASSES];
    int g = blockIdx.x, t = threadIdx.x;
    float c = cntf[g];
    if (c < 1.f) c = 1.f;
    pl[t] = sums[g * 64 + t] / c;
    __syncthreads();
    float a = b1[t];
    for (int f = 0; f < 64; ++f) a += pl[f] * w1[f * 64 + t];
    gl[t] = a > 0.f ? a : 0.f;
    __syncthreads();
    if (t < NCLASSES) {
        float a2 = b2[t];
        for (int f = 0; f < 64; ++f) a2 += gl[f] * w2[f * NCLASSES + t];
        lg[t] = a2;
    }
    __syncthreads();
    if (t < NCLASSES) {
        float m = lg[0];
        for (int i = 1; i < NCLASSES; ++i) m = fmaxf(m, lg[i]);
        float s = 0.f;
        for (int i = 0; i < NCLASSES; ++i) s += expf(lg[i] - m);
        out[g * NCLASSES + t] = lg[t] - m - logf(s);
    }
}

// ---------------- host ----------------

extern "C" void kernel_launch(void* const* d_in, const int* in_sizes, int n_in,
                              void* d_out, int out_size, void* d_ws, size_t ws_size,
                              hipStream_t stream) {
    const float* x   = (const float*)d_in[0];
    const int*   ei  = (const int*)d_in[1];
    const int*   bat = (const int*)d_in[2];
    const float* W1  = (const float*)d_in[3];
    const float* th1 = (const float*)d_in[4];
    const float* b1  = (const float*)d_in[5];
    const float* Ws  = (const float*)d_in[6];
    const float* ths = (const float*)d_in[7];
    const float* bs  = (const float*)d_in[8];
    const float* l1w = (const float*)d_in[9];
    const float* l1b = (const float*)d_in[10];
    const float* l2w = (const float*)d_in[11];
    const float* l2b = (const float*)d_in[12];
    float* out = (float*)d_out;

    const int n  = in_sizes[2];
    const int ne = in_sizes[1] / 2;
    const int* erow = ei;
    const int* ecol = ei + ne;

    const int PSd = (n + 1) * 8;  // dwords per feature plane (16 bf16/row, +1 zero row)

    // workspace carve
    char* w = (char*)d_ws;
    size_t off = 0;
    auto carve = [&](size_t bytes) {
        void* p = w + off;
        off += align256(bytes);
        return p;
    };
    const size_t ne_pad = (size_t)ne + 7 * (size_t)n + 8;  // max padded records
    int*   deg    = (int*)carve((size_t)n * 4);
    int*   rowptr = (int*)carve((size_t)(n + 1) * 4);
    int*   cursor = (int*)carve((size_t)n * 4);
    int*   bsum   = (int*)carve(1024 * 4);
    int*   ccol   = (int*)carve(ne_pad * 4);
    float* dinv   = (float*)carve((size_t)n * 4);
    float* d2     = (float*)carve((size_t)n * 4);
    float* rdinv  = (float*)carve((size_t)n * 4);
    float* coeff  = (float*)carve(3 * KORD * 4);
    float* sums   = (float*)carve((size_t)NGRAPHS * 64 * 4);
    float* cntf   = (float*)carve((size_t)NGRAPHS * 4);
    float* outacc = (float*)carve((size_t)n * 64 * 4);  // doubles as H
    unsigned* slabs = (unsigned*)carve((size_t)7 * 4 * PSd * 4);
    auto slab = [&](int s) { return slabs + (size_t)s * 4 * PSd; };
    (void)ws_size; (void)n_in; (void)out_size;

    const int nb256e = (ne + 255) / 256;
    const int nb256n = (n + 255) / 256;

    hipMemsetAsync(deg, 0, (size_t)n * 4, stream);
    hipMemsetAsync(sums, 0, (size_t)NGRAPHS * 64 * 4, stream);
    hipMemsetAsync(cntf, 0, (size_t)NGRAPHS * 4, stream);

    k_deg<<<nb256e, 256, 0, stream>>>(erow, deg, ne);
    k_dinv<<<nb256n, 256, 0, stream>>>(deg, dinv, d2, rdinv, n);
    k_scan1<<<nb256n, 256, 0, stream>>>(deg, rowptr, bsum, n);
    k_scan2<<<1, 1024, 0, stream>>>(bsum, nb256n);
    k_scan3<<<nb256n, 256, 0, stream>>>(rowptr, cursor, bsum, deg, n);
    k_filln<<<(int)((ne_pad + 255) / 256), 256, 0, stream>>>(ccol, (int)ne_pad, n);
    k_fill<<<nb256e, 256, 0, stream>>>(erow, ecol, cursor, ccol, ne);
    k_zrow<<<1, 256, 0, stream>>>(slabs, PSd, n);
    k_coeff<<<1, 64, 0, stream>>>(th1, ths, coeff);

    const int RB = (n + 3) / 4;             // 4 rows per block
    const int pgrid = 8 * ((RB + 1) / 2);   // xcd-slot major grid
    const int n32 = n * 32;
    const int ab = (n32 + 255) / 256;

    for (int l = 0; l < 3; ++l) {
        const float* cf = coeff + l * KORD;
        const float* bias = (l == 0) ? b1 : bs + (l - 1) * HID;

        if (l == 0)
            k_gemm<FIN><<<(n + 63) / 64, 256, 0, stream>>>(x, W1, slab(0), dinv, n, PSd);
        else
            k_gemm<HID><<<(n + 63) / 64, 256, 0, stream>>>(outacc, Ws + (size_t)(l - 1) * HID * HID,
                                                           slab(0), dinv, n, PSd);

        k_prop<true><<<pgrid, 256, 0, stream>>>(rowptr, ccol, slab(0), nullptr, slab(1), d2, n, PSd, RB);
        for (int k = 2; k <= 6; ++k)
            k_prop<false><<<pgrid, 256, 0, stream>>>(rowptr, ccol, slab(k - 1), slab(k - 2), slab(k),
                                                     d2, n, PSd, RB);
        k_acc<false><<<ab, 256, 0, stream>>>(slab(0), slab(1), slab(2), slab(3), slab(4), slab(5),
                                             slab(6), cf, nullptr, rdinv, outacc, n, PSd);
        for (int k = 7; k <= 13; ++k)
            k_prop<false><<<pgrid, 256, 0, stream>>>(rowptr, ccol, slab((k - 1) % 7), slab((k - 2) % 7),
                                                     slab(k % 7), d2, n, PSd, RB);
        k_acc<true><<<ab, 256, 0, stream>>>(slab(0), slab(1), slab(2), slab(3), slab(4), slab(5),
                                            slab(6), cf + 7, bias, rdinv, outacc, n, PSd);
    }

    const int poolwaves = (n + 31) / 32;
    const int poolblocks = (poolwaves * 64 + 255) / 256;
    k_pool<<<poolblocks, 256, 0, stream>>>(outacc, bat, sums, cntf, n);
    k_head<<<NGRAPHS, 64, 0, stream>>>(sums, cntf, l1w, l1b, l2w, l2b, out);
}

// Round 7
// 3919.616 us; speedup vs baseline: 1.3451x; 1.3451x over previous
//
#include <hip/hip_runtime.h>

#define NN 100000
#define NE 1600000
#define FIN 128
#define HID 64
#define HEADS 8
#define KORD 14
#define NGRAPHS 128
#define NCLASSES 10

static inline size_t align256(size_t x) { return (x + 255) & ~(size_t)255; }

// round-to-nearest-even f32 -> bf16 (as uint16 in low bits)
__device__ __forceinline__ unsigned bfr(float x) {
    unsigned u = __float_as_uint(x);
    return (u + 0x7fffu + ((u >> 16) & 1u)) >> 16;
}
__device__ __forceinline__ unsigned bfpack(float lo, float hi) {
    return bfr(lo) | (bfr(hi) << 16);
}
__device__ __forceinline__ float bflo(unsigned u) { return __uint_as_float(u << 16); }
__device__ __forceinline__ float bfhi(unsigned u) { return __uint_as_float(u & 0xffff0000u); }

// ---------------- setup kernels ----------------

__global__ void k_deg(const int* __restrict__ row, int* __restrict__ deg, int ne) {
    int e = blockIdx.x * 256 + threadIdx.x;
    if (e < ne) atomicAdd(&deg[row[e]], 1);
}

// dinv = rsqrt(max(deg,1)); d2 = 1/max(deg,1); rdinv = sqrt(max(deg,1))
__global__ void k_dinv(const int* __restrict__ deg, float* __restrict__ dinv,
                       float* __restrict__ d2, float* __restrict__ rdinv, int n) {
    int i = blockIdx.x * 256 + threadIdx.x;
    if (i < n) {
        float d = (float)deg[i];
        if (d < 1.f) d = 1.f;
        dinv[i] = rsqrtf(d);
        d2[i] = 1.f / d;
        rdinv[i] = sqrtf(d);
    }
}

// exclusive scan phase 1: per-block scan of PADDED degrees ((deg+7)&~7)
__global__ void k_scan1(const int* __restrict__ deg, int* __restrict__ rowptr,
                        int* __restrict__ bsum, int n) {
    __shared__ int s[256];
    int t = threadIdx.x;
    int i = blockIdx.x * 256 + t;
    int v = (i < n) ? ((deg[i] + 7) & ~7) : 0;
    s[t] = v;
    __syncthreads();
    for (int off = 1; off < 256; off <<= 1) {
        int add = (t >= off) ? s[t - off] : 0;
        __syncthreads();
        s[t] += add;
        __syncthreads();
    }
    if (i < n) rowptr[i] = s[t] - v;  // exclusive within block
    if (t == 255) bsum[blockIdx.x] = s[255];
}

// phase 2: single-block exclusive scan of block sums (nb <= 1024)
__global__ void k_scan2(int* __restrict__ bsum, int nb) {
    __shared__ int s[1024];
    int t = threadIdx.x;
    int v = (t < nb) ? bsum[t] : 0;
    s[t] = v;
    __syncthreads();
    for (int off = 1; off < 1024; off <<= 1) {
        int add = (t >= off) ? s[t - off] : 0;
        __syncthreads();
        s[t] += add;
        __syncthreads();
    }
    if (t < nb) bsum[t] = s[t] - v;  // exclusive
}

// phase 3: add block offsets; init cursor; write rowptr[n] (total padded edges)
__global__ void k_scan3(int* __restrict__ rowptr, int* __restrict__ cursor,
                        const int* __restrict__ bsum, const int* __restrict__ deg, int n) {
    int i = blockIdx.x * 256 + threadIdx.x;
    if (i < n) {
        int v = rowptr[i] + bsum[i >> 8];
        rowptr[i] = v;
        cursor[i] = v;
        if (i == n - 1) rowptr[n] = v + ((deg[i] + 7) & ~7);
    }
}

// pre-fill ccol with the zero-row index n (pad slots read row n == 0)
__global__ void k_filln(int* __restrict__ ccol, int npad, int n) {
    int i = blockIdx.x * 256 + threadIdx.x;
    if (i < npad) ccol[i] = n;
}

// fill CSR cols (weights are implicit in S-space)
__global__ void k_fill(const int* __restrict__ row, const int* __restrict__ col,
                       int* __restrict__ cursor, int* __restrict__ ccol, int ne) {
    int e = blockIdx.x * 256 + threadIdx.x;
    if (e >= ne) return;
    int pos = atomicAdd(&cursor[row[e]], 1);
    ccol[pos] = col[e];
}

// zero the pad row (row n) of all 7 slabs x 4 planes
__global__ void k_zrow(unsigned* __restrict__ slabs, int PSd, int n) {
    int t = threadIdx.x;
    if (t >= 7 * 4 * 8) return;
    int sp = t >> 3;  // slab*4+plane, 0..27
    int q = t & 7;
    slabs[(size_t)sp * PSd + (size_t)n * 8 + q] = 0;
}

// coeff[l][k] = mean over heads of theta[l][h][k]
__global__ void k_coeff(const float* __restrict__ th1, const float* __restrict__ ths,
                        float* __restrict__ coeff) {
    int i = threadIdx.x;
    if (i >= 3 * KORD) return;
    int l = i / KORD, k = i % KORD;
    const float* t = (l == 0) ? th1 : ths + (l - 1) * HEADS * KORD;
    float s = 0.f;
    for (int h = 0; h < HEADS; ++h) s += t[h * KORD + k];
    coeff[i] = s * (1.f / HEADS);
}

// ---------------- main compute kernels ----------------

// S0 = dinv * (h @ W), written as bf16 into 4 feature planes of slab0.
// block = 256 threads, tile = 64 rows x 64 cols, thread computes 4 rows x 4 cols.
template <int F>
__global__ __launch_bounds__(256) void k_gemm(const float* __restrict__ h,
                                              const float* __restrict__ W,
                                              unsigned* __restrict__ slab0,
                                              const float* __restrict__ dinv,
                                              int n, int PSd) {
    __shared__ __align__(16) float Wl[F * 64];
    __shared__ float hl[64][F + 1];
    int tid = threadIdx.x;
    int row0 = blockIdx.x * 64;
    int nrows = n - row0;
    if (nrows > 64) nrows = 64;

    for (int i = tid; i < F * 64; i += 256) Wl[i] = W[i];
    for (int i = tid; i < nrows * F; i += 256) hl[i / F][i % F] = h[(size_t)row0 * F + i];
    __syncthreads();

    int rq = tid >> 4;        // 0..15 -> rows rq*4 .. rq*4+3
    int c0 = (tid & 15) * 4;  // col group
    float4 acc0 = {0, 0, 0, 0}, acc1 = {0, 0, 0, 0}, acc2 = {0, 0, 0, 0}, acc3 = {0, 0, 0, 0};
#pragma unroll 4
    for (int f = 0; f < F; ++f) {
        const float4 wv = *(const float4*)&Wl[f * 64 + c0];
        float h0 = hl[rq * 4 + 0][f];
        float h1 = hl[rq * 4 + 1][f];
        float h2 = hl[rq * 4 + 2][f];
        float h3 = hl[rq * 4 + 3][f];
        acc0.x = fmaf(h0, wv.x, acc0.x); acc0.y = fmaf(h0, wv.y, acc0.y);
        acc0.z = fmaf(h0, wv.z, acc0.z); acc0.w = fmaf(h0, wv.w, acc0.w);
        acc1.x = fmaf(h1, wv.x, acc1.x); acc1.y = fmaf(h1, wv.y, acc1.y);
        acc1.z = fmaf(h1, wv.z, acc1.z); acc1.w = fmaf(h1, wv.w, acc1.w);
        acc2.x = fmaf(h2, wv.x, acc2.x); acc2.y = fmaf(h2, wv.y, acc2.y);
        acc2.z = fmaf(h2, wv.z, acc2.z); acc2.w = fmaf(h2, wv.w, acc2.w);
        acc3.x = fmaf(h3, wv.x, acc3.x); acc3.y = fmaf(h3, wv.y, acc3.y);
        acc3.z = fmaf(h3, wv.z, acc3.z); acc3.w = fmaf(h3, wv.w, acc3.w);
    }
    int rem = nrows - rq * 4;
    float4 accs[4] = {acc0, acc1, acc2, acc3};
    int pl = c0 >> 4;
    int qd = (c0 & 15) >> 1;  // even dword offset within plane row
#pragma unroll
    for (int r = 0; r < 4; ++r) {
        if (r < rem) {
            int row = row0 + rq * 4 + r;
            float dv = dinv[row];
            size_t dw = (size_t)pl * PSd + (size_t)row * 8 + qd;
            uint2 p;
            p.x = bfpack(accs[r].x * dv, accs[r].y * dv);
            p.y = bfpack(accs[r].z * dv, accs[r].w * dv);
            *(uint2*)(slab0 + dw) = p;
        }
    }
}

// S-space Chebyshev prop, one feature plane (16 feats = 8 dwords) per block, 4 rows/block.
// Wave = one row; lanes: g = lane>>3 (edge slot 0..7), fl = lane&7 (feature dword).
// 32 edges per iteration via 4 independent gathers (MLP=4); pad groups read zero row n.
// FIRST: S1 = -d2 * sum ; else: S_k = -2*d2*sum - S_{k-2}
// blockIdx&7 -> XCD slot; plane = slot>>1 pins each plane to one XCD pair (L2 residency).
template <bool FIRST>
__global__ __launch_bounds__(256) void k_prop(const int* __restrict__ rowptr,
                                              const int* __restrict__ ccol,
                                              const unsigned* __restrict__ src,
                                              const unsigned* __restrict__ prev,
                                              unsigned* __restrict__ dst,
                                              const float* __restrict__ d2arr,
                                              int n, int PSd, int RB) {
    int blk = blockIdx.x;
    int slot = blk & 7;
    int pl = slot >> 1;
    int rb = (blk >> 3) * 2 + (slot & 1);
    if (rb >= RB) return;
    int wave = threadIdx.x >> 6;
    int lane = threadIdx.x & 63;
    int r = rb * 4 + wave;
    if (r >= n) return;
    r = __builtin_amdgcn_readfirstlane(r);
    const unsigned* sp = src + (size_t)pl * PSd;
    const int e0 = __builtin_amdgcn_readfirstlane(rowptr[r]);
    const int e1 = __builtin_amdgcn_readfirstlane(rowptr[r + 1]);
    const int g = lane >> 3;
    const int fl = lane & 7;
    float a0 = 0.f, a1 = 0.f;
    for (int e = e0; e < e1; e += 32) {
        int c0 = ccol[e + g];  // group 0 always valid (rows padded to x8)
        int c1 = (e + 8 < e1) ? ccol[e + 8 + g] : n;
        int c2 = (e + 16 < e1) ? ccol[e + 16 + g] : n;
        int c3 = (e + 24 < e1) ? ccol[e + 24 + g] : n;
        unsigned u0 = sp[(size_t)c0 * 8 + fl];
        unsigned u1 = sp[(size_t)c1 * 8 + fl];
        unsigned u2 = sp[(size_t)c2 * 8 + fl];
        unsigned u3 = sp[(size_t)c3 * 8 + fl];
        a0 += bflo(u0); a1 += bfhi(u0);
        a0 += bflo(u1); a1 += bfhi(u1);
        a0 += bflo(u2); a1 += bfhi(u2);
        a0 += bflo(u3); a1 += bfhi(u3);
    }
    a0 += __shfl_xor(a0, 8, 64);  a1 += __shfl_xor(a1, 8, 64);
    a0 += __shfl_xor(a0, 16, 64); a1 += __shfl_xor(a1, 16, 64);
    a0 += __shfl_xor(a0, 32, 64); a1 += __shfl_xor(a1, 32, 64);
    if (lane >= 8) return;
    float d2 = d2arr[r];
    size_t di = (size_t)pl * PSd + (size_t)r * 8 + fl;
    float sx, sy;
    if (FIRST) {
        sx = -d2 * a0;
        sy = -d2 * a1;
    } else {
        unsigned pu = prev[di];
        sx = fmaf(-2.f * d2, a0, -bflo(pu));
        sy = fmaf(-2.f * d2, a1, -bfhi(pu));
    }
    dst[di] = bfpack(sx, sy);
}

// accumulate 7 Chebyshev terms: out(+)= rdinv[r] * sum_j cf[j]*S_j ; FINAL adds bias+relu.
template <bool FINAL>
__global__ __launch_bounds__(256) void k_acc(const unsigned* __restrict__ s0,
                                             const unsigned* __restrict__ s1,
                                             const unsigned* __restrict__ s2,
                                             const unsigned* __restrict__ s3,
                                             const unsigned* __restrict__ s4,
                                             const unsigned* __restrict__ s5,
                                             const unsigned* __restrict__ s6,
                                             const float* __restrict__ cf,
                                             const float* __restrict__ bias,
                                             const float* __restrict__ rdinv,
                                             float* __restrict__ outacc, int n, int PSd) {
    int i = blockIdx.x * 256 + threadIdx.x;
    if (i >= n * 32) return;
    int r = i >> 5;
    int f0 = (i & 31) * 2;
    size_t dw = (size_t)(f0 >> 4) * PSd + (size_t)r * 8 + ((f0 & 15) >> 1);
    float c0 = cf[0], c1 = cf[1], c2 = cf[2], c3 = cf[3], c4 = cf[4], c5 = cf[5], c6 = cf[6];
    unsigned u;
    float ax, ay;
    u = s0[dw]; ax = c0 * bflo(u); ay = c0 * bfhi(u);
    u = s1[dw]; ax = fmaf(c1, bflo(u), ax); ay = fmaf(c1, bfhi(u), ay);
    u = s2[dw]; ax = fmaf(c2, bflo(u), ax); ay = fmaf(c2, bfhi(u), ay);
    u = s3[dw]; ax = fmaf(c3, bflo(u), ax); ay = fmaf(c3, bfhi(u), ay);
    u = s4[dw]; ax = fmaf(c4, bflo(u), ax); ay = fmaf(c4, bfhi(u), ay);
    u = s5[dw]; ax = fmaf(c5, bflo(u), ax); ay = fmaf(c5, bfhi(u), ay);
    u = s6[dw]; ax = fmaf(c6, bflo(u), ax); ay = fmaf(c6, bfhi(u), ay);
    float rd = rdinv[r];
    ax *= rd;
    ay *= rd;
    float2* op = (float2*)outacc + i;
    if (FINAL) {
        float2 pv = *op;
        float vx = pv.x + ax + bias[f0];
        float vy = pv.y + ay + bias[f0 + 1];
        *op = make_float2(vx > 0.f ? vx : 0.f, vy > 0.f ? vy : 0.f);
    } else {
        *op = make_float2(ax, ay);
    }
}

// run-length compressed segment sum over sorted batch; wave = 32 nodes, lane = feature
__global__ void k_pool(const float* __restrict__ h, const int* __restrict__ batch,
                       float* __restrict__ sums, float* __restrict__ cntf, int n) {
    int wid = (blockIdx.x * blockDim.x + threadIdx.x) >> 6;
    int lane = threadIdx.x & 63;
    int start = wid * 32;
    if (start >= n) return;
    int end = start + 32;
    if (end > n) end = n;
    float acc = 0.f;
    int run = 0;
    int g = batch[start];
    for (int i = start; i < end; ++i) {
        int gi = batch[i];
        if (gi != g) {
            atomicAdd(&sums[g * 64 + lane], acc);
            if (lane == 0) atomicAdd(&cntf[g], (float)run);
            acc = 0.f;
            run = 0;
            g = gi;
        }
        acc += h[(size_t)i * 64 + lane];
        run++;
    }
    atomicAdd(&sums[g * 64 + lane], acc);
    if (lane == 0) atomicAdd(&cntf[g], (float)run);
}

// per-graph head: pooled = sums/cnt ; g = relu(pooled@w1+b1) ; logits = g@w2+b2 ; log_softmax
__global__ void k_head(const float* __restrict__ sums, const float* __restrict__ cntf,
                       const float* __restrict__ w1, const float* __restrict__ b1,
                       const float* __restrict__ w2, const float* __restrict__ b2,
                       float* __restrict__ out) {
    __shared__ float pl[64], gl[64], lg[NCLASSES];
    int g = blockIdx.x, t = threadIdx.x;
    float c = cntf[g];
    if (c < 1.f) c = 1.f;
    pl[t] = sums[g * 64 + t] / c;
    __syncthreads();
    float a = b1[t];
    for (int f = 0; f < 64; ++f) a += pl[f] * w1[f * 64 + t];
    gl[t] = a > 0.f ? a : 0.f;
    __syncthreads();
    if (t < NCLASSES) {
        float a2 = b2[t];
        for (int f = 0; f < 64; ++f) a2 += gl[f] * w2[f * NCLASSES + t];
        lg[t] = a2;
    }
    __syncthreads();
    if (t < NCLASSES) {
        float m = lg[0];
        for (int i = 1; i < NCLASSES; ++i) m = fmaxf(m, lg[i]);
        float s = 0.f;
        for (int i = 0; i < NCLASSES; ++i) s += expf(lg[i] - m);
        out[g * NCLASSES + t] = lg[t] - m - logf(s);
    }
}

// ---------------- host ----------------

extern "C" void kernel_launch(void* const* d_in, const int* in_sizes, int n_in,
                              void* d_out, int out_size, void* d_ws, size_t ws_size,
                              hipStream_t stream) {
    const float* x   = (const float*)d_in[0];
    const int*   ei  = (const int*)d_in[1];
    const int*   bat = (const int*)d_in[2];
    const float* W1  = (const float*)d_in[3];
    const float* th1 = (const float*)d_in[4];
    const float* b1  = (const float*)d_in[5];
    const float* Ws  = (const float*)d_in[6];
    const float* ths = (const float*)d_in[7];
    const float* bs  = (const float*)d_in[8];
    const float* l1w = (const float*)d_in[9];
    const float* l1b = (const float*)d_in[10];
    const float* l2w = (const float*)d_in[11];
    const float* l2b = (const float*)d_in[12];
    float* out = (float*)d_out;

    const int n  = in_sizes[2];
    const int ne = in_sizes[1] / 2;
    const int* erow = ei;
    const int* ecol = ei + ne;

    const int PSd = (n + 1) * 8;  // dwords per feature plane (16 bf16/row, +1 zero row)

    // workspace carve
    char* w = (char*)d_ws;
    size_t off = 0;
    auto carve = [&](size_t bytes) {
        void* p = w + off;
        off += align256(bytes);
        return p;
    };
    const size_t ne_pad = (size_t)ne + 7 * (size_t)n + 8;  // max padded records
    int*   deg    = (int*)carve((size_t)n * 4);
    int*   rowptr = (int*)carve((size_t)(n + 1) * 4);
    int*   cursor = (int*)carve((size_t)n * 4);
    int*   bsum   = (int*)carve(1024 * 4);
    int*   ccol   = (int*)carve(ne_pad * 4);
    float* dinv   = (float*)carve((size_t)n * 4);
    float* d2     = (float*)carve((size_t)n * 4);
    float* rdinv  = (float*)carve((size_t)n * 4);
    float* coeff  = (float*)carve(3 * KORD * 4);
    float* sums   = (float*)carve((size_t)NGRAPHS * 64 * 4);
    float* cntf   = (float*)carve((size_t)NGRAPHS * 4);
    float* outacc = (float*)carve((size_t)n * 64 * 4);  // doubles as H
    unsigned* slabs = (unsigned*)carve((size_t)7 * 4 * PSd * 4);
    auto slab = [&](int s) { return slabs + (size_t)s * 4 * PSd; };
    (void)ws_size; (void)n_in; (void)out_size;

    const int nb256e = (ne + 255) / 256;
    const int nb256n = (n + 255) / 256;

    hipMemsetAsync(deg, 0, (size_t)n * 4, stream);
    hipMemsetAsync(sums, 0, (size_t)NGRAPHS * 64 * 4, stream);
    hipMemsetAsync(cntf, 0, (size_t)NGRAPHS * 4, stream);

    k_deg<<<nb256e, 256, 0, stream>>>(erow, deg, ne);
    k_dinv<<<nb256n, 256, 0, stream>>>(deg, dinv, d2, rdinv, n);
    k_scan1<<<nb256n, 256, 0, stream>>>(deg, rowptr, bsum, n);
    k_scan2<<<1, 1024, 0, stream>>>(bsum, nb256n);
    k_scan3<<<nb256n, 256, 0, stream>>>(rowptr, cursor, bsum, deg, n);
    k_filln<<<(int)((ne_pad + 255) / 256), 256, 0, stream>>>(ccol, (int)ne_pad, n);
    k_fill<<<nb256e, 256, 0, stream>>>(erow, ecol, cursor, ccol, ne);
    k_zrow<<<1, 256, 0, stream>>>(slabs, PSd, n);
    k_coeff<<<1, 64, 0, stream>>>(th1, ths, coeff);

    const int RB = (n + 3) / 4;             // 4 rows per block
    const int pgrid = 8 * ((RB + 1) / 2);   // xcd-slot major grid
    const int n32 = n * 32;
    const int ab = (n32 + 255) / 256;

    for (int l = 0; l < 3; ++l) {
        const float* cf = coeff + l * KORD;
        const float* bias = (l == 0) ? b1 : bs + (l - 1) * HID;

        if (l == 0)
            k_gemm<FIN><<<(n + 63) / 64, 256, 0, stream>>>(x, W1, slab(0), dinv, n, PSd);
        else
            k_gemm<HID><<<(n + 63) / 64, 256, 0, stream>>>(outacc, Ws + (size_t)(l - 1) * HID * HID,
                                                           slab(0), dinv, n, PSd);

        k_prop<true><<<pgrid, 256, 0, stream>>>(rowptr, ccol, slab(0), nullptr, slab(1), d2, n, PSd, RB);
        for (int k = 2; k <= 6; ++k)
            k_prop<false><<<pgrid, 256, 0, stream>>>(rowptr, ccol, slab(k - 1), slab(k - 2), slab(k),
                                                     d2, n, PSd, RB);
        k_acc<false><<<ab, 256, 0, stream>>>(slab(0), slab(1), slab(2), slab(3), slab(4), slab(5),
                                             slab(6), cf, nullptr, rdinv, outacc, n, PSd);
        for (int k = 7; k <= 13; ++k)
            k_prop<false><<<pgrid, 256, 0, stream>>>(rowptr, ccol, slab((k - 1) % 7), slab((k - 2) % 7),
                                                     slab(k % 7), d2, n, PSd, RB);
        k_acc<true><<<ab, 256, 0, stream>>>(slab(0), slab(1), slab(2), slab(3), slab(4), slab(5),
                                            slab(6), cf + 7, bias, rdinv, outacc, n, PSd);
    }

    const int poolwaves = (n + 31) / 32;
    const int poolblocks = (poolwaves * 64 + 255) / 256;
    k_pool<<<poolblocks, 256, 0, stream>>>(outacc, bat, sums, cntf, n);
    k_head<<<NGRAPHS, 64, 0, stream>>>(sums, cntf, l1w, l1b, l2w, l2b, out);
}

// Round 8
// 1876.984 us; speedup vs baseline: 2.8088x; 2.0883x over previous
//
#include <hip/hip_runtime.h>

#define NN 100000
#define NE 1600000
#define FIN 128
#define HID 64
#define HEADS 8
#define KORD 14
#define NGRAPHS 128
#define NCLASSES 10

static inline size_t align256(size_t x) { return (x + 255) & ~(size_t)255; }

// round-to-nearest-even f32 -> bf16 (as uint16 in low bits)
__device__ __forceinline__ unsigned bfr(float x) {
    unsigned u = __float_as_uint(x);
    return (u + 0x7fffu + ((u >> 16) & 1u)) >> 16;
}
__device__ __forceinline__ unsigned bfpack(float lo, float hi) {
    return bfr(lo) | (bfr(hi) << 16);
}
__device__ __forceinline__ float bflo(unsigned u) { return __uint_as_float(u << 16); }
__device__ __forceinline__ float bfhi(unsigned u) { return __uint_as_float(u & 0xffff0000u); }

// ---------------- setup kernels ----------------

__global__ void k_deg(const int* __restrict__ row, int* __restrict__ deg, int ne) {
    int e = blockIdx.x * 256 + threadIdx.x;
    if (e < ne) atomicAdd(&deg[row[e]], 1);
}

// dinv = rsqrt(max(deg,1)); d2 = 1/max(deg,1); rdinv = sqrt(max(deg,1))
__global__ void k_dinv(const int* __restrict__ deg, float* __restrict__ dinv,
                       float* __restrict__ d2, float* __restrict__ rdinv, int n) {
    int i = blockIdx.x * 256 + threadIdx.x;
    if (i < n) {
        float d = (float)deg[i];
        if (d < 1.f) d = 1.f;
        dinv[i] = rsqrtf(d);
        d2[i] = 1.f / d;
        rdinv[i] = sqrtf(d);
    }
}

// exclusive scan phase 1: per-block scan of PADDED degrees ((deg+7)&~7)
__global__ void k_scan1(const int* __restrict__ deg, int* __restrict__ rowptr,
                        int* __restrict__ bsum, int n) {
    __shared__ int s[256];
    int t = threadIdx.x;
    int i = blockIdx.x * 256 + t;
    int v = (i < n) ? ((deg[i] + 7) & ~7) : 0;
    s[t] = v;
    __syncthreads();
    for (int off = 1; off < 256; off <<= 1) {
        int add = (t >= off) ? s[t - off] : 0;
        __syncthreads();
        s[t] += add;
        __syncthreads();
    }
    if (i < n) rowptr[i] = s[t] - v;  // exclusive within block
    if (t == 255) bsum[blockIdx.x] = s[255];
}

// phase 2: single-block exclusive scan of block sums (nb <= 1024)
__global__ void k_scan2(int* __restrict__ bsum, int nb) {
    __shared__ int s[1024];
    int t = threadIdx.x;
    int v = (t < nb) ? bsum[t] : 0;
    s[t] = v;
    __syncthreads();
    for (int off = 1; off < 1024; off <<= 1) {
        int add = (t >= off) ? s[t - off] : 0;
        __syncthreads();
        s[t] += add;
        __syncthreads();
    }
    if (t < nb) bsum[t] = s[t] - v;  // exclusive
}

// phase 3: add block offsets; init cursor; write rowptr[n] (total padded edges)
__global__ void k_scan3(int* __restrict__ rowptr, int* __restrict__ cursor,
                        const int* __restrict__ bsum, const int* __restrict__ deg, int n) {
    int i = blockIdx.x * 256 + threadIdx.x;
    if (i < n) {
        int v = rowptr[i] + bsum[i >> 8];
        rowptr[i] = v;
        cursor[i] = v;
        if (i == n - 1) rowptr[n] = v + ((deg[i] + 7) & ~7);
    }
}

// pre-fill ccol with the zero-row index n (pad slots read row n == 0)
__global__ void k_filln(int* __restrict__ ccol, int npad, int n) {
    int i = blockIdx.x * 256 + threadIdx.x;
    if (i < npad) ccol[i] = n;
}

// fill CSR cols (weights are implicit in S-space)
__global__ void k_fill(const int* __restrict__ row, const int* __restrict__ col,
                       int* __restrict__ cursor, int* __restrict__ ccol, int ne) {
    int e = blockIdx.x * 256 + threadIdx.x;
    if (e >= ne) return;
    int pos = atomicAdd(&cursor[row[e]], 1);
    ccol[pos] = col[e];
}

// zero the pad row (row n) of all 7 slabs (each slab = (n+1) x 32 dwords)
__global__ void k_zrow(unsigned* __restrict__ slabs, int n) {
    int t = threadIdx.x;
    if (t >= 7 * 32) return;
    int sp = t >> 5;  // slab 0..6
    int q = t & 31;
    slabs[(size_t)sp * (size_t)(n + 1) * 32 + (size_t)n * 32 + q] = 0;
}

// coeff[l][k] = mean over heads of theta[l][h][k]
__global__ void k_coeff(const float* __restrict__ th1, const float* __restrict__ ths,
                        float* __restrict__ coeff) {
    int i = threadIdx.x;
    if (i >= 3 * KORD) return;
    int l = i / KORD, k = i % KORD;
    const float* t = (l == 0) ? th1 : ths + (l - 1) * HEADS * KORD;
    float s = 0.f;
    for (int h = 0; h < HEADS; ++h) s += t[h * KORD + k];
    coeff[i] = s * (1.f / HEADS);
}

// ---------------- main compute kernels ----------------

// S0 = dinv * (h @ W), written as bf16 [n][64] (= [n][32] dwords) slab.
// block = 256 threads, tile = 64 rows x 64 cols, thread computes 4 rows x 4 cols.
template <int F>
__global__ __launch_bounds__(256) void k_gemm(const float* __restrict__ h,
                                              const float* __restrict__ W,
                                              unsigned* __restrict__ slab0,
                                              const float* __restrict__ dinv, int n) {
    __shared__ __align__(16) float Wl[F * 64];
    __shared__ float hl[64][F + 1];
    int tid = threadIdx.x;
    int row0 = blockIdx.x * 64;
    int nrows = n - row0;
    if (nrows > 64) nrows = 64;

    for (int i = tid; i < F * 64; i += 256) Wl[i] = W[i];
    for (int i = tid; i < nrows * F; i += 256) hl[i / F][i % F] = h[(size_t)row0 * F + i];
    __syncthreads();

    int rq = tid >> 4;        // 0..15 -> rows rq*4 .. rq*4+3
    int c0 = (tid & 15) * 4;  // col group
    float4 acc0 = {0, 0, 0, 0}, acc1 = {0, 0, 0, 0}, acc2 = {0, 0, 0, 0}, acc3 = {0, 0, 0, 0};
#pragma unroll 4
    for (int f = 0; f < F; ++f) {
        const float4 wv = *(const float4*)&Wl[f * 64 + c0];
        float h0 = hl[rq * 4 + 0][f];
        float h1 = hl[rq * 4 + 1][f];
        float h2 = hl[rq * 4 + 2][f];
        float h3 = hl[rq * 4 + 3][f];
        acc0.x = fmaf(h0, wv.x, acc0.x); acc0.y = fmaf(h0, wv.y, acc0.y);
        acc0.z = fmaf(h0, wv.z, acc0.z); acc0.w = fmaf(h0, wv.w, acc0.w);
        acc1.x = fmaf(h1, wv.x, acc1.x); acc1.y = fmaf(h1, wv.y, acc1.y);
        acc1.z = fmaf(h1, wv.z, acc1.z); acc1.w = fmaf(h1, wv.w, acc1.w);
        acc2.x = fmaf(h2, wv.x, acc2.x); acc2.y = fmaf(h2, wv.y, acc2.y);
        acc2.z = fmaf(h2, wv.z, acc2.z); acc2.w = fmaf(h2, wv.w, acc2.w);
        acc3.x = fmaf(h3, wv.x, acc3.x); acc3.y = fmaf(h3, wv.y, acc3.y);
        acc3.z = fmaf(h3, wv.z, acc3.z); acc3.w = fmaf(h3, wv.w, acc3.w);
    }
    int rem = nrows - rq * 4;
    float4 accs[4] = {acc0, acc1, acc2, acc3};
    int qd = c0 >> 1;  // even dword offset in the 32-dword row
#pragma unroll
    for (int r = 0; r < 4; ++r) {
        if (r < rem) {
            int row = row0 + rq * 4 + r;
            float dv = dinv[row];
            uint2 p;
            p.x = bfpack(accs[r].x * dv, accs[r].y * dv);
            p.y = bfpack(accs[r].z * dv, accs[r].w * dv);
            *(uint2*)(slab0 + (size_t)row * 32 + qd) = p;
        }
    }
}

// S-space Chebyshev prop. Wave = one row; low half lanes: edges 0-3 of the 8-block,
// high half: edges 4-7. Each lane loads 1 dword (2 bf16 feats) per edge -> 128 B/edge
// coalesced, 4 independent gathers in flight. Rows padded to x8 with col=n (zero row).
// FIRST: S1 = -d2 * sum ; else: S_k = -2*d2*sum - S_{k-2}
template <bool FIRST>
__global__ __launch_bounds__(256) void k_prop(const int* __restrict__ rowptr,
                                              const int* __restrict__ ccol,
                                              const unsigned* __restrict__ src,
                                              const unsigned* __restrict__ prev,
                                              unsigned* __restrict__ dst,
                                              const float* __restrict__ d2arr, int n) {
    int r = (blockIdx.x * 256 + threadIdx.x) >> 6;
    int lane = threadIdx.x & 63;
    if (r >= n) return;
    r = __builtin_amdgcn_readfirstlane(r);
    const int e0 = __builtin_amdgcn_readfirstlane(rowptr[r]);
    const int e1 = __builtin_amdgcn_readfirstlane(rowptr[r + 1]);
    const bool hi = lane >= 32;
    const int fl = lane & 31;  // feature dword (2 bf16)
    float a0 = 0.f, a1 = 0.f;
    for (int e = e0; e < e1; e += 8) {
        const int4* q = (const int4*)(ccol + e);
        int4 q0 = q[0];
        int4 q1 = q[1];
        int cA = hi ? q1.x : q0.x;
        int cB = hi ? q1.y : q0.y;
        int cC = hi ? q1.z : q0.z;
        int cD = hi ? q1.w : q0.w;
        unsigned uA = src[(size_t)cA * 32 + fl];
        unsigned uB = src[(size_t)cB * 32 + fl];
        unsigned uC = src[(size_t)cC * 32 + fl];
        unsigned uD = src[(size_t)cD * 32 + fl];
        a0 += bflo(uA); a1 += bfhi(uA);
        a0 += bflo(uB); a1 += bfhi(uB);
        a0 += bflo(uC); a1 += bfhi(uC);
        a0 += bflo(uD); a1 += bfhi(uD);
    }
    // combine the two halves (edge-set A + edge-set B partials)
    a0 += __shfl_xor(a0, 32, 64);
    a1 += __shfl_xor(a1, 32, 64);
    if (hi) return;
    float d2 = d2arr[r];
    size_t di = (size_t)r * 32 + fl;
    float sx, sy;
    if (FIRST) {
        sx = -d2 * a0;
        sy = -d2 * a1;
    } else {
        unsigned pu = prev[di];
        sx = fmaf(-2.f * d2, a0, -bflo(pu));
        sy = fmaf(-2.f * d2, a1, -bfhi(pu));
    }
    dst[di] = bfpack(sx, sy);
}

// accumulate 7 Chebyshev terms: out(+)= rdinv[r] * sum_j cf[j]*S_j ; FINAL adds bias+relu.
// slabs are [n][32] dwords contiguous -> dword index == thread index.
template <bool FINAL>
__global__ __launch_bounds__(256) void k_acc(const unsigned* __restrict__ s0,
                                             const unsigned* __restrict__ s1,
                                             const unsigned* __restrict__ s2,
                                             const unsigned* __restrict__ s3,
                                             const unsigned* __restrict__ s4,
                                             const unsigned* __restrict__ s5,
                                             const unsigned* __restrict__ s6,
                                             const float* __restrict__ cf,
                                             const float* __restrict__ bias,
                                             const float* __restrict__ rdinv,
                                             float* __restrict__ outacc, int n) {
    int i = blockIdx.x * 256 + threadIdx.x;
    if (i >= n * 32) return;
    float c0 = cf[0], c1 = cf[1], c2 = cf[2], c3 = cf[3], c4 = cf[4], c5 = cf[5], c6 = cf[6];
    unsigned u;
    float ax, ay;
    u = s0[i]; ax = c0 * bflo(u); ay = c0 * bfhi(u);
    u = s1[i]; ax = fmaf(c1, bflo(u), ax); ay = fmaf(c1, bfhi(u), ay);
    u = s2[i]; ax = fmaf(c2, bflo(u), ax); ay = fmaf(c2, bfhi(u), ay);
    u = s3[i]; ax = fmaf(c3, bflo(u), ax); ay = fmaf(c3, bfhi(u), ay);
    u = s4[i]; ax = fmaf(c4, bflo(u), ax); ay = fmaf(c4, bfhi(u), ay);
    u = s5[i]; ax = fmaf(c5, bflo(u), ax); ay = fmaf(c5, bfhi(u), ay);
    u = s6[i]; ax = fmaf(c6, bflo(u), ax); ay = fmaf(c6, bfhi(u), ay);
    float rd = rdinv[i >> 5];
    ax *= rd;
    ay *= rd;
    float2* op = (float2*)outacc + i;
    if (FINAL) {
        int f0 = (i & 31) * 2;
        float2 pv = *op;
        float vx = pv.x + ax + bias[f0];
        float vy = pv.y + ay + bias[f0 + 1];
        *op = make_float2(vx > 0.f ? vx : 0.f, vy > 0.f ? vy : 0.f);
    } else {
        *op = make_float2(ax, ay);
    }
}

// run-length compressed segment sum over sorted batch; wave = 32 nodes, lane = feature
__global__ void k_pool(const float* __restrict__ h, const int* __restrict__ batch,
                       float* __restrict__ sums, float* __restrict__ cntf, int n) {
    int wid = (blockIdx.x * blockDim.x + threadIdx.x) >> 6;
    int lane = threadIdx.x & 63;
    int start = wid * 32;
    if (start >= n) return;
    int end = start + 32;
    if (end > n) end = n;
    float acc = 0.f;
    int run = 0;
    int g = batch[start];
    for (int i = start; i < end; ++i) {
        int gi = batch[i];
        if (gi != g) {
            atomicAdd(&sums[g * 64 + lane], acc);
            if (lane == 0) atomicAdd(&cntf[g], (float)run);
            acc = 0.f;
            run = 0;
            g = gi;
        }
        acc += h[(size_t)i * 64 + lane];
        run++;
    }
    atomicAdd(&sums[g * 64 + lane], acc);
    if (lane == 0) atomicAdd(&cntf[g], (float)run);
}

// per-graph head: pooled = sums/cnt ; g = relu(pooled@w1+b1) ; logits = g@w2+b2 ; log_softmax
__global__ void k_head(const float* __restrict__ sums, const float* __restrict__ cntf,
                       const float* __restrict__ w1, const float* __restrict__ b1,
                       const float* __restrict__ w2, const float* __restrict__ b2,
                       float* __restrict__ out) {
    __shared__ float pl[64], gl[64], lg[NCLASSES];
    int g = blockIdx.x, t = threadIdx.x;
    float c = cntf[g];
    if (c < 1.f) c = 1.f;
    pl[t] = sums[g * 64 + t] / c;
    __syncthreads();
    float a = b1[t];
    for (int f = 0; f < 64; ++f) a += pl[f] * w1[f * 64 + t];
    gl[t] = a > 0.f ? a : 0.f;
    __syncthreads();
    if (t < NCLASSES) {
        float a2 = b2[t];
        for (int f = 0; f < 64; ++f) a2 += gl[f] * w2[f * NCLASSES + t];
        lg[t] = a2;
    }
    __syncthreads();
    if (t < NCLASSES) {
        float m = lg[0];
        for (int i = 1; i < NCLASSES; ++i) m = fmaxf(m, lg[i]);
        float s = 0.f;
        for (int i = 0; i < NCLASSES; ++i) s += expf(lg[i] - m);
        out[g * NCLASSES + t] = lg[t] - m - logf(s);
    }
}

// ---------------- host ----------------

extern "C" void kernel_launch(void* const* d_in, const int* in_sizes, int n_in,
                              void* d_out, int out_size, void* d_ws, size_t ws_size,
                              hipStream_t stream) {
    const float* x   = (const float*)d_in[0];
    const int*   ei  = (const int*)d_in[1];
    const int*   bat = (const int*)d_in[2];
    const float* W1  = (const float*)d_in[3];
    const float* th1 = (const float*)d_in[4];
    const float* b1  = (const float*)d_in[5];
    const float* Ws  = (const float*)d_in[6];
    const float* ths = (const float*)d_in[7];
    const float* bs  = (const float*)d_in[8];
    const float* l1w = (const float*)d_in[9];
    const float* l1b = (const float*)d_in[10];
    const float* l2w = (const float*)d_in[11];
    const float* l2b = (const float*)d_in[12];
    float* out = (float*)d_out;

    const int n  = in_sizes[2];
    const int ne = in_sizes[1] / 2;
    const int* erow = ei;
    const int* ecol = ei + ne;

    // workspace carve
    char* w = (char*)d_ws;
    size_t off = 0;
    auto carve = [&](size_t bytes) {
        void* p = w + off;
        off += align256(bytes);
        return p;
    };
    const size_t ne_pad = (size_t)ne + 7 * (size_t)n + 8;  // max padded records
    const size_t slabd = (size_t)(n + 1) * 32;             // dwords per slab
    int*   deg    = (int*)carve((size_t)n * 4);
    int*   rowptr = (int*)carve((size_t)(n + 1) * 4);
    int*   cursor = (int*)carve((size_t)n * 4);
    int*   bsum   = (int*)carve(1024 * 4);
    int*   ccol   = (int*)carve(ne_pad * 4);
    float* dinv   = (float*)carve((size_t)n * 4);
    float* d2     = (float*)carve((size_t)n * 4);
    float* rdinv  = (float*)carve((size_t)n * 4);
    float* coeff  = (float*)carve(3 * KORD * 4);
    float* sums   = (float*)carve((size_t)NGRAPHS * 64 * 4);
    float* cntf   = (float*)carve((size_t)NGRAPHS * 4);
    float* outacc = (float*)carve((size_t)n * 64 * 4);  // doubles as H
    unsigned* slabs = (unsigned*)carve(7 * slabd * 4);
    auto slab = [&](int s) { return slabs + (size_t)s * slabd; };
    (void)ws_size; (void)n_in; (void)out_size;

    const int nb256e = (ne + 255) / 256;
    const int nb256n = (n + 255) / 256;

    hipMemsetAsync(deg, 0, (size_t)n * 4, stream);
    hipMemsetAsync(sums, 0, (size_t)NGRAPHS * 64 * 4, stream);
    hipMemsetAsync(cntf, 0, (size_t)NGRAPHS * 4, stream);

    k_deg<<<nb256e, 256, 0, stream>>>(erow, deg, ne);
    k_dinv<<<nb256n, 256, 0, stream>>>(deg, dinv, d2, rdinv, n);
    k_scan1<<<nb256n, 256, 0, stream>>>(deg, rowptr, bsum, n);
    k_scan2<<<1, 1024, 0, stream>>>(bsum, nb256n);
    k_scan3<<<nb256n, 256, 0, stream>>>(rowptr, cursor, bsum, deg, n);
    k_filln<<<(int)((ne_pad + 255) / 256), 256, 0, stream>>>(ccol, (int)ne_pad, n);
    k_fill<<<nb256e, 256, 0, stream>>>(erow, ecol, cursor, ccol, ne);
    k_zrow<<<1, 256, 0, stream>>>(slabs, n);
    k_coeff<<<1, 64, 0, stream>>>(th1, ths, coeff);

    const int pb = (n + 3) / 4;       // 4 waves (rows) per 256-thread block
    const int n32 = n * 32;
    const int ab = (n32 + 255) / 256;

    for (int l = 0; l < 3; ++l) {
        const float* cf = coeff + l * KORD;
        const float* bias = (l == 0) ? b1 : bs + (l - 1) * HID;

        if (l == 0)
            k_gemm<FIN><<<(n + 63) / 64, 256, 0, stream>>>(x, W1, slab(0), dinv, n);
        else
            k_gemm<HID><<<(n + 63) / 64, 256, 0, stream>>>(outacc, Ws + (size_t)(l - 1) * HID * HID,
                                                           slab(0), dinv, n);

        k_prop<true><<<pb, 256, 0, stream>>>(rowptr, ccol, slab(0), nullptr, slab(1), d2, n);
        for (int k = 2; k <= 6; ++k)
            k_prop<false><<<pb, 256, 0, stream>>>(rowptr, ccol, slab(k - 1), slab(k - 2), slab(k), d2, n);
        k_acc<false><<<ab, 256, 0, stream>>>(slab(0), slab(1), slab(2), slab(3), slab(4), slab(5),
                                             slab(6), cf, nullptr, rdinv, outacc, n);
        for (int k = 7; k <= 13; ++k)
            k_prop<false><<<pb, 256, 0, stream>>>(rowptr, ccol, slab((k - 1) % 7), slab((k - 2) % 7),
                                                  slab(k % 7), d2, n);
        k_acc<true><<<ab, 256, 0, stream>>>(slab(0), slab(1), slab(2), slab(3), slab(4), slab(5),
                                            slab(6), cf + 7, bias, rdinv, outacc, n);
    }

    const int poolwaves = (n + 31) / 32;
    const int poolblocks = (poolwaves * 64 + 255) / 256;
    k_pool<<<poolblocks, 256, 0, stream>>>(outacc, bat, sums, cntf, n);
    k_head<<<NGRAPHS, 64, 0, stream>>>(sums, cntf, l1w, l1b, l2w, l2b, out);
}